// Round 8
// baseline (235.021 us; speedup 1.0000x reference)
//
#include <hip/hip_runtime.h>
#include <hip/hip_bf16.h>

typedef __bf16 bf16x8 __attribute__((ext_vector_type(8)));
typedef float f32x16 __attribute__((ext_vector_type(16)));

#define NQ     10
#define M_ROWS 16384
#define N_COLS 1024
#define K_DIM  4096

// ---------------------------------------------------------------- helpers
__device__ __forceinline__ void gload_lds16(const __hip_bfloat16* g, __hip_bfloat16* l) {
  __builtin_amdgcn_global_load_lds(
      (const __attribute__((address_space(1))) void*)g,
      (__attribute__((address_space(3))) void*)l,
      16, 0, 0);
}

// relu both + pack to 2xbf16 (lo=a, hi=b) in exactly 3 VALU ops (R6 win).
__device__ __forceinline__ unsigned pkrelu(float a, float b) {
  float x = fmaxf(a, 0.f), y = fmaxf(b, 0.f);
  unsigned r;
  asm("v_cvt_pk_bf16_f32 %0, %1, %2" : "=v"(r) : "v"(x), "v"(y));
  return r;
}

__device__ __forceinline__ bf16x8 mkfrag(unsigned a, unsigned b, unsigned c, unsigned d) {
  union { unsigned u[4]; bf16x8 v; } f;
  f.u[0] = a; f.u[1] = b; f.u[2] = c; f.u[3] = d;
  return f.v;
}

// ---------------------------------------------------------------- prep (fused)
// blocks [0,4096): W2 fp32->bf16
// blocks [4096,4112): Wq slot s holds W1 row pi(s) (pi = in-32-block bit perm:
//   out[4]=s[3], out[3]=s[2], out[2]=s[4], out[1:0]=s[1:0]) so the mini-MFMA's
//   D-reg layout IS the main-MFMA A-frag layout (no permlane, no reorder).
// blocks [4112,4176): Qb[row][0..15] = bf16(q_j(row)) closed-form, 0 pad
__global__ void __launch_bounds__(256) prep(const float* __restrict__ W1,
                                            const float* __restrict__ W2,
                                            const float* __restrict__ x,
                                            const float* __restrict__ qp,
                                            __hip_bfloat16* __restrict__ W2b,
                                            __hip_bfloat16* __restrict__ Wq,
                                            __hip_bfloat16* __restrict__ Qb) {
  const int b = blockIdx.x;
  const int tid = threadIdx.x;
  if (b < 4096) {
    int i = (b * 256 + tid) * 4;
    float4 v = *(const float4*)(W2 + i);
    union { __hip_bfloat16 h[4]; uint2 u; } p;
    p.h[0] = __float2bfloat16(v.x);
    p.h[1] = __float2bfloat16(v.y);
    p.h[2] = __float2bfloat16(v.z);
    p.h[3] = __float2bfloat16(v.w);
    *(uint2*)(W2b + i) = p.u;
  } else if (b < 4112) {
    int slot = (b - 4096) * 256 + tid;
    int s5 = slot & 31;
    int src = (slot & ~31) | (((s5 >> 3) & 1) << 4) | (((s5 >> 2) & 1) << 3) |
              (((s5 >> 4) & 1) << 2) | (s5 & 3);
    union { __hip_bfloat16 h[16]; uint4 u[2]; } p;
#pragma unroll
    for (int j = 0; j < NQ; j++) p.h[j] = __float2bfloat16(W1[src * NQ + j]);
#pragma unroll
    for (int j = NQ; j < 16; j++) p.h[j] = __float2bfloat16(0.f);
    *(uint4*)(Wq + slot * 16) = p.u[0];
    *(uint4*)(Wq + slot * 16 + 8) = p.u[1];
  } else {
    int row = (b - 4112) * 256 + tid;
    float c[NQ];
#pragma unroll
    for (int j = 0; j < NQ; j++) c[j] = cosf(x[row * NQ + j] + qp[j]);
    float q[NQ];
    float prod19 = 1.f;
#pragma unroll
    for (int j = 1; j < NQ; j++) prod19 *= c[j];
    q[0] = prod19;
    float pref = c[0];
#pragma unroll
    for (int k = 1; k < NQ; k++) { pref *= c[k]; q[k] = pref; }
    union { __hip_bfloat16 h[16]; uint4 u[2]; } p;
#pragma unroll
    for (int j = 0; j < NQ; j++) p.h[j] = __float2bfloat16(q[j]);
#pragma unroll
    for (int j = NQ; j < 16; j++) p.h[j] = __float2bfloat16(0.f);
    *(uint4*)(Qb + row * 16) = p.u[0];
    *(uint4*)(Qb + row * 16 + 8) = p.u[1];
  }
}

// ---------------------------------------------------------------- fused gemm
// C = relu(Q @ W1^T) @ W2^T.
// R8: R6's body (R7's manual pipeline REGRESSED -- compiler already
// interleaves within the barrier region; reverted) at 256x128 tiles,
// grid 512 = 2 BLOCKS/CU for cross-block overlap.  R6's counters
// (MfmaUtil 53 + VALUBusy 39, wall 4900 cyc/tile vs 2324 MFMA content)
// showed 1 block/CU barrier-locks all waves into the same phase: drain +
// post-barrier LDS burst has nothing to overlap with.  Co-resident blocks
// are barrier-independent (m97-structure's proven overlap source).
// 512 threads / 8 waves, 4 (rows) x 2 (cols), wave tile 64x64, acc[2][2].
// __launch_bounds__(512,4): 4 waves/SIMD -> VGPR capped at 128 (R6 used 116,
// acc halved, ~100 expected).  LDS = 2 x 16 KB Bs only (64 KB/CU at 2 blk).
// Cost: mini redundancy x2 per CU (+258 cyc on 2324 floor) -- accepted.
// Each XCD owns one 128-col B panel (1 MB, L2-fit) x 64 row tiles.
// A never touches LDS (R4); pi-permuted Wq (R5); HW cvt_pk relu/pack (R6);
// ONE __syncthreads per K-tile.
__global__ void __launch_bounds__(512, 4) gemm_fused(const __hip_bfloat16* __restrict__ Qb,
                                                     const __hip_bfloat16* __restrict__ Wq,
                                                     const __hip_bfloat16* __restrict__ B,
                                                     float* __restrict__ C) {
  __shared__ __align__(16) __hip_bfloat16 Bs[2][128 * 64];   // 2 x 16 KB

  const int tid  = threadIdx.x;
  const int wave = tid >> 6;           // 0..7
  const int lane = tid & 63;
  const int l31  = lane & 31;
  const int l5   = lane >> 5;
  const int l7   = l31 & 7;
  const int wrow = (wave >> 1) * 64;   // 4 row bands x 64
  const int wn   = (wave & 1) * 64;    // 2 col halves x 64

  // XCD decode: XCD d owns col panel d*128 (1 MB, L2-fit) x 64 row tiles
  const int L    = blockIdx.x;          // 512 blocks
  const int xcd  = L & 7;
  const int idx  = L >> 3;              // 0..63
  const int col0 = xcd * 128;
  const int row0 = idx * 256;

  const int ldrow = lane >> 3;                       // staging row 0..7
  const int ldc   = (((lane & 7) ^ ldrow) << 3);     // XOR slot for Bs staging

  // hoisted ds_read addressing: swizzle chunk per kki + lane row base
  const int ch0 = (((0 + l5) ^ l7) << 3);
  const int ch1 = (((2 + l5) ^ l7) << 3);
  const int ch2 = (((4 + l5) ^ l7) << 3);
  const int ch3 = (((6 + l5) ^ l7) << 3);
  const int bsoff = (wn + l31) * 64;    // element offset of this lane's row

  // mini-GEMM B-operand frags (loop-invariant): this wave's 2 row-groups
  const bf16x8 qbr0 = *(const bf16x8*)(Qb + (row0 + wrow +  0 + l31) * 16 + l5 * 8);
  const bf16x8 qbr1 = *(const bf16x8*)(Qb + (row0 + wrow + 32 + l31) * 16 + l5 * 8);

  // persistent zero C-operand for minis (zeroed once, never overwritten)
  f32x16 kZero;
#pragma unroll
  for (int r = 0; r < 16; r++) kZero[r] = 0.f;

  f32x16 acc[2][2];
#pragma unroll
  for (int i = 0; i < 2; i++)
#pragma unroll
    for (int j = 0; j < 2; j++)
#pragma unroll
      for (int r = 0; r < 16; r++) acc[i][j][r] = 0.f;

  // A-fragments: rg x {even,odd} kki of the current kt (rebuilt twice per tile)
  bf16x8 frE0, frO0, frE1, frO1;

#define MFMA_BF16 __builtin_amdgcn_mfma_f32_32x32x16_bf16

#define WQF(t, kt) (*(const bf16x8*)(Wq + ((t) * 64 + (kt) * 32 + l31) * 16 + l5 * 8))

  // wave w, instr i stages Bs rows [w*16+i*8, +8) x 64 k (XOR-swizzled via source)
#define STAGE(bw, ts, i)                                                              \
  gload_lds16(B + (col0 + wave * 16 + (i) * 8 + ldrow) * K_DIM + (ts) * 64 + ldc,     \
              &Bs[bw][(wave * 16 + (i) * 8) * 64])

  // mini h-MFMA for one row-group -> even/odd-kki A-frags (pi-permuted Wq
  // makes D-reg order == frag order; kZero avoids per-mini zero-init)
#define MINIFR(QB, WQ, FRE, FRO) do {                                                 \
    f32x16 d_ = MFMA_BF16(WQ, QB, kZero, 0, 0, 0);                                    \
    FRE = mkfrag(pkrelu(d_[0],  d_[1]),  pkrelu(d_[2],  d_[3]),                       \
                 pkrelu(d_[8],  d_[9]),  pkrelu(d_[10], d_[11]));                     \
    FRO = mkfrag(pkrelu(d_[4],  d_[5]),  pkrelu(d_[6],  d_[7]),                       \
                 pkrelu(d_[12], d_[13]), pkrelu(d_[14], d_[15]));                     \
  } while (0)

  // one K=16 step: 2 Bs reads + 4 MFMAs (FR0 = rg0 frag, FR1 = rg1 frag)
#define MAINK(cur, CH, FR0, FR1) do {                                                 \
    const __hip_bfloat16* bp_ = &Bs[cur][bsoff + (CH)];                               \
    const bf16x8 bb0 = *(const bf16x8*)(bp_ +    0);                                  \
    const bf16x8 bb1 = *(const bf16x8*)(bp_ + 2048);                                  \
    acc[0][0] = MFMA_BF16(FR0, bb0, acc[0][0], 0, 0, 0);                              \
    acc[0][1] = MFMA_BF16(FR0, bb1, acc[0][1], 0, 0, 0);                              \
    acc[1][0] = MFMA_BF16(FR1, bb0, acc[1][0], 0, 0, 0);                              \
    acc[1][1] = MFMA_BF16(FR1, bb1, acc[1][1], 0, 0, 0);                              \
  } while (0)

  // one K-tile: stage Bs for t+1, prefetch Wq[t+1], minis+mains for t.
  // Tail (t=63) prefetch/stage reads spill into adjacent workspace regions
  // (reads only, results unused) -- no fault, no clobber.
#define TILE(cur, nxt, WQ0, WQ1, WQP0, WQP1, t) do {                                  \
    STAGE(nxt, (t) + 1, 0); STAGE(nxt, (t) + 1, 1);                                   \
    WQP0 = WQF((t) + 1, 0); WQP1 = WQF((t) + 1, 1);                                   \
    MINIFR(qbr0, WQ0, frE0, frO0);                                                    \
    MINIFR(qbr1, WQ0, frE1, frO1);                                                    \
    MAINK(cur, ch0, frE0, frE1);                                                      \
    MAINK(cur, ch1, frO0, frO1);                                                      \
    MINIFR(qbr0, WQ1, frE0, frO0);                                                    \
    MINIFR(qbr1, WQ1, frE1, frO1);                                                    \
    MAINK(cur, ch2, frE0, frE1);                                                      \
    MAINK(cur, ch3, frO0, frO1);                                                      \
    __syncthreads();                                                                  \
  } while (0)

  // ---------------- prologue: stage Bs tile 0, load Wq tile 0 frags
  STAGE(0, 0, 0); STAGE(0, 0, 1);
  bf16x8 wqC0 = WQF(0, 0), wqC1 = WQF(0, 1);
  bf16x8 wqN0, wqN1;
  __syncthreads();   // drains stage loads (compiler emits vmcnt(0) before barrier)

  // ---------------- main loop: 64 K-tiles, unrolled by 2 for static buffers
  for (int u = 0; u < 32; u++) {
    TILE(0, 1, wqC0, wqC1, wqN0, wqN1, 2 * u);
    TILE(1, 0, wqN0, wqN1, wqC0, wqC1, 2 * u + 1);
  }

  // ---------------- epilogue: C/D layout col=lane&31, row=(reg&3)+8*(reg>>2)+4*l5
#pragma unroll
  for (int rg = 0; rg < 2; rg++) {
#pragma unroll
    for (int fn = 0; fn < 2; fn++) {
      const int colb = col0 + wn + fn * 32 + l31;
      const int rowb = row0 + wrow + rg * 32 + 4 * l5;
#pragma unroll
      for (int reg = 0; reg < 16; reg++) {
        int row = rowb + (reg & 3) + 8 * (reg >> 2);
        C[row * N_COLS + colb] = acc[rg][fn][reg];
      }
    }
  }
}

// ---------------------------------------------------------------- launch
extern "C" void kernel_launch(void* const* d_in, const int* in_sizes, int n_in,
                              void* d_out, int out_size, void* d_ws, size_t ws_size,
                              hipStream_t stream) {
  const float* x  = (const float*)d_in[0];   // 32*512*10
  const float* qp = (const float*)d_in[1];   // 10
  const float* W1 = (const float*)d_in[2];   // 4096*10
  const float* W2 = (const float*)d_in[3];   // 1024*4096
  float* out = (float*)d_out;                // 32*512*1024 fp32

  char* ws = (char*)d_ws;
  __hip_bfloat16* W2b = (__hip_bfloat16*)ws;                 // 8388608 B
  __hip_bfloat16* Wq  = (__hip_bfloat16*)(ws + 8388608);     // 131072 B (4096x16)
  __hip_bfloat16* Qb  = (__hip_bfloat16*)(ws + 8519680);     // 524288 B (16384x16)

  prep<<<4176, 256, 0, stream>>>(W1, W2, x, qp, W2b, Wq, Qb);
  gemm_fused<<<(M_ROWS / 256) * (N_COLS / 128), 512, 0, stream>>>(Qb, Wq, W2b, out);
}

// Round 10
// 214.000 us; speedup vs baseline: 1.0982x; 1.0982x over previous
//
#include <hip/hip_runtime.h>
#include <hip/hip_bf16.h>

typedef __bf16 bf16x8 __attribute__((ext_vector_type(8)));
typedef float f32x16 __attribute__((ext_vector_type(16)));

#define NQ     10
#define M_ROWS 16384
#define N_COLS 1024
#define K_DIM  4096

// ---------------------------------------------------------------- helpers
__device__ __forceinline__ void gload_lds16(const __hip_bfloat16* g, __hip_bfloat16* l) {
  __builtin_amdgcn_global_load_lds(
      (const __attribute__((address_space(1))) void*)g,
      (__attribute__((address_space(3))) void*)l,
      16, 0, 0);
}

// relu both + pack to 2xbf16 (lo=a, hi=b): 2x v_max_f32 + HW v_cvt_pk_bf16_f32.
// (R6 win, PROVEN.  R9's post-pack v_pk_max_i16 variant produced NaN on HW --
// reverted; do not re-attempt without disasm evidence.)
__device__ __forceinline__ unsigned pkrelu(float a, float b) {
  float x = fmaxf(a, 0.f), y = fmaxf(b, 0.f);
  unsigned r;
  asm("v_cvt_pk_bf16_f32 %0, %1, %2" : "=v"(r) : "v"(x), "v"(y));
  return r;
}

__device__ __forceinline__ bf16x8 mkfrag(unsigned a, unsigned b, unsigned c, unsigned d) {
  union { unsigned u[4]; bf16x8 v; } f;
  f.u[0] = a; f.u[1] = b; f.u[2] = c; f.u[3] = d;
  return f.v;
}

// ---------------------------------------------------------------- prep (fused)
// blocks [0,4096): W2 fp32->bf16
// blocks [4096,4112): Wq slot s holds W1 row pi(s) (pi = in-32-block bit perm:
//   out[4]=s[3], out[3]=s[2], out[2]=s[4], out[1:0]=s[1:0]) so the mini-MFMA's
//   D-reg layout IS the main-MFMA A-frag layout (no permlane, no reorder).
// blocks [4112,4176): Qb[row][0..15] = bf16(q_j(row)) closed-form, 0 pad
__global__ void __launch_bounds__(256) prep(const float* __restrict__ W1,
                                            const float* __restrict__ W2,
                                            const float* __restrict__ x,
                                            const float* __restrict__ qp,
                                            __hip_bfloat16* __restrict__ W2b,
                                            __hip_bfloat16* __restrict__ Wq,
                                            __hip_bfloat16* __restrict__ Qb) {
  const int b = blockIdx.x;
  const int tid = threadIdx.x;
  if (b < 4096) {
    int i = (b * 256 + tid) * 4;
    float4 v = *(const float4*)(W2 + i);
    union { __hip_bfloat16 h[4]; uint2 u; } p;
    p.h[0] = __float2bfloat16(v.x);
    p.h[1] = __float2bfloat16(v.y);
    p.h[2] = __float2bfloat16(v.z);
    p.h[3] = __float2bfloat16(v.w);
    *(uint2*)(W2b + i) = p.u;
  } else if (b < 4112) {
    int slot = (b - 4096) * 256 + tid;
    int s5 = slot & 31;
    int src = (slot & ~31) | (((s5 >> 3) & 1) << 4) | (((s5 >> 2) & 1) << 3) |
              (((s5 >> 4) & 1) << 2) | (s5 & 3);
    union { __hip_bfloat16 h[16]; uint4 u[2]; } p;
#pragma unroll
    for (int j = 0; j < NQ; j++) p.h[j] = __float2bfloat16(W1[src * NQ + j]);
#pragma unroll
    for (int j = NQ; j < 16; j++) p.h[j] = __float2bfloat16(0.f);
    *(uint4*)(Wq + slot * 16) = p.u[0];
    *(uint4*)(Wq + slot * 16 + 8) = p.u[1];
  } else {
    int row = (b - 4112) * 256 + tid;
    float c[NQ];
#pragma unroll
    for (int j = 0; j < NQ; j++) c[j] = cosf(x[row * NQ + j] + qp[j]);
    float q[NQ];
    float prod19 = 1.f;
#pragma unroll
    for (int j = 1; j < NQ; j++) prod19 *= c[j];
    q[0] = prod19;
    float pref = c[0];
#pragma unroll
    for (int k = 1; k < NQ; k++) { pref *= c[k]; q[k] = pref; }
    union { __hip_bfloat16 h[16]; uint4 u[2]; } p;
#pragma unroll
    for (int j = 0; j < NQ; j++) p.h[j] = __float2bfloat16(q[j]);
#pragma unroll
    for (int j = NQ; j < 16; j++) p.h[j] = __float2bfloat16(0.f);
    *(uint4*)(Qb + row * 16) = p.u[0];
    *(uint4*)(Qb + row * 16 + 8) = p.u[1];
  }
}

// ---------------------------------------------------------------- fused gemm
// C = relu(Q @ W1^T) @ W2^T.
// R10: R6's per-wave body (PROVEN 131 us) at 128x256 tiles, 256 threads /
// 4 waves (2 rows x 2 cols, wave tile 64x128, acc[2][4]), grid 512 =
// 2 BLOCKS/CU.  Halving BM (not BN like R8) keeps per-CU mini count (32/tile)
// and LDS-read count (128/tile) IDENTICAL to R6 -- minis scale with BN-share,
// B-reads with BN -- while splitting the CU into two independent barrier
// domains: a SIMD pairs waves from different blocks, so one block's tile-end
// drain + post-barrier LDS burst overlaps the other's MFMA run.  Same
// 2 waves/SIMD as R6; the gain is barrier decoupling, not wave count.
// LDS = 2 blocks x 64 KB = 128 KB/CU.  A never touches LDS (R4);
// pi-permuted Wq (R5); HW cvt_pk relu/pack (R6); ONE __syncthreads/K-tile.
// Each XCD owns one 256-col B panel (2 MB, L2-fit) x 128 row tiles.
__global__ void __launch_bounds__(256, 2) gemm_fused(const __hip_bfloat16* __restrict__ Qb,
                                                     const __hip_bfloat16* __restrict__ Wq,
                                                     const __hip_bfloat16* __restrict__ B,
                                                     float* __restrict__ C) {
  __shared__ __align__(16) __hip_bfloat16 Bs[2][256 * 64];   // 2 x 32 KB

  const int tid  = threadIdx.x;
  const int wave = tid >> 6;           // 0..3
  const int lane = tid & 63;
  const int l31  = lane & 31;
  const int l5   = lane >> 5;
  const int l7   = l31 & 7;
  const int wrow = (wave >> 1) * 64;   // 2 row bands x 64
  const int wn   = (wave & 1) * 128;   // 2 col halves x 128

  // XCD decode: 2 XCDs per 256-col B panel, 64+64 row tiles of 128
  const int L    = blockIdx.x;          // 512 blocks
  const int xcd  = L & 7;
  const int idx  = L >> 3;              // 0..63
  const int col0 = (xcd >> 1) * 256;
  const int row0 = (((xcd & 1) << 6) | idx) * 128;   // 128 row tiles

  const int ldrow = lane >> 3;                       // staging row 0..7
  const int ldc   = (((lane & 7) ^ ldrow) << 3);     // XOR slot for Bs staging

  // hoisted ds_read addressing: swizzle chunk per kki + wave/lane row base
  const int ch0 = (((0 + l5) ^ l7) << 3);
  const int ch1 = (((2 + l5) ^ l7) << 3);
  const int ch2 = (((4 + l5) ^ l7) << 3);
  const int ch3 = (((6 + l5) ^ l7) << 3);
  const int bsoff = (wn + l31) * 64;    // element offset of this lane's row

  // mini-GEMM B-operand frags (loop-invariant): this wave's 2 row-groups
  const bf16x8 qbr0 = *(const bf16x8*)(Qb + (row0 + wrow +  0 + l31) * 16 + l5 * 8);
  const bf16x8 qbr1 = *(const bf16x8*)(Qb + (row0 + wrow + 32 + l31) * 16 + l5 * 8);

  // persistent zero C-operand for minis (zeroed once, never overwritten)
  f32x16 kZero;
#pragma unroll
  for (int r = 0; r < 16; r++) kZero[r] = 0.f;

  f32x16 acc[2][4];
#pragma unroll
  for (int i = 0; i < 2; i++)
#pragma unroll
    for (int j = 0; j < 4; j++)
#pragma unroll
      for (int r = 0; r < 16; r++) acc[i][j][r] = 0.f;

  // A-fragments: rg x {even,odd} kki of the current kt (rebuilt twice per tile)
  bf16x8 frE0, frO0, frE1, frO1;

#define MFMA_BF16 __builtin_amdgcn_mfma_f32_32x32x16_bf16

#define WQF(t, kt) (*(const bf16x8*)(Wq + ((t) * 64 + (kt) * 32 + l31) * 16 + l5 * 8))

  // wave w, instr i stages Bs rows [w*64+i*8, +8) x 64 k (XOR-swizzled source);
  // 4 waves x 8 instrs cover all 256 rows
#define STAGE(bw, ts, i)                                                              \
  gload_lds16(B + (col0 + wave * 64 + (i) * 8 + ldrow) * K_DIM + (ts) * 64 + ldc,     \
              &Bs[bw][(wave * 64 + (i) * 8) * 64])

  // mini h-MFMA for one row-group -> even/odd-kki A-frags (pi-permuted Wq
  // makes D-reg order == frag order; kZero avoids per-mini zero-init)
#define MINIFR(QB, WQ, FRE, FRO) do {                                                 \
    f32x16 d_ = MFMA_BF16(WQ, QB, kZero, 0, 0, 0);                                    \
    FRE = mkfrag(pkrelu(d_[0],  d_[1]),  pkrelu(d_[2],  d_[3]),                       \
                 pkrelu(d_[8],  d_[9]),  pkrelu(d_[10], d_[11]));                     \
    FRO = mkfrag(pkrelu(d_[4],  d_[5]),  pkrelu(d_[6],  d_[7]),                       \
                 pkrelu(d_[12], d_[13]), pkrelu(d_[14], d_[15]));                     \
  } while (0)

  // one K=16 step: 4 Bs reads + 8 MFMAs (FR0 = rg0 frag, FR1 = rg1 frag).
  // f*2048 elements = 4096B const offsets fold into ds_read offset: immediates.
#define MAINK(cur, CH, FR0, FR1) do {                                                 \
    const __hip_bfloat16* bp_ = &Bs[cur][bsoff + (CH)];                               \
    const bf16x8 bb0 = *(const bf16x8*)(bp_ +    0);                                  \
    const bf16x8 bb1 = *(const bf16x8*)(bp_ + 2048);                                  \
    const bf16x8 bb2 = *(const bf16x8*)(bp_ + 4096);                                  \
    const bf16x8 bb3 = *(const bf16x8*)(bp_ + 6144);                                  \
    acc[0][0] = MFMA_BF16(FR0, bb0, acc[0][0], 0, 0, 0);                              \
    acc[0][1] = MFMA_BF16(FR0, bb1, acc[0][1], 0, 0, 0);                              \
    acc[0][2] = MFMA_BF16(FR0, bb2, acc[0][2], 0, 0, 0);                              \
    acc[0][3] = MFMA_BF16(FR0, bb3, acc[0][3], 0, 0, 0);                              \
    acc[1][0] = MFMA_BF16(FR1, bb0, acc[1][0], 0, 0, 0);                              \
    acc[1][1] = MFMA_BF16(FR1, bb1, acc[1][1], 0, 0, 0);                              \
    acc[1][2] = MFMA_BF16(FR1, bb2, acc[1][2], 0, 0, 0);                              \
    acc[1][3] = MFMA_BF16(FR1, bb3, acc[1][3], 0, 0, 0);                              \
  } while (0)

  // one K-tile: stage Bs for t+1, prefetch Wq[t+1], minis+mains for t.
  // Tail (t=63) prefetch/stage reads spill into adjacent workspace regions
  // (reads only, results unused) -- no fault, no clobber.
#define TILE(cur, nxt, WQ0, WQ1, WQP0, WQP1, t) do {                                  \
    STAGE(nxt, (t) + 1, 0); STAGE(nxt, (t) + 1, 1);                                   \
    STAGE(nxt, (t) + 1, 2); STAGE(nxt, (t) + 1, 3);                                   \
    STAGE(nxt, (t) + 1, 4); STAGE(nxt, (t) + 1, 5);                                   \
    STAGE(nxt, (t) + 1, 6); STAGE(nxt, (t) + 1, 7);                                   \
    WQP0 = WQF((t) + 1, 0); WQP1 = WQF((t) + 1, 1);                                   \
    MINIFR(qbr0, WQ0, frE0, frO0);                                                    \
    MINIFR(qbr1, WQ0, frE1, frO1);                                                    \
    MAINK(cur, ch0, frE0, frE1);                                                      \
    MAINK(cur, ch1, frO0, frO1);                                                      \
    MINIFR(qbr0, WQ1, frE0, frO0);                                                    \
    MINIFR(qbr1, WQ1, frE1, frO1);                                                    \
    MAINK(cur, ch2, frE0, frE1);                                                      \
    MAINK(cur, ch3, frO0, frO1);                                                      \
    __syncthreads();                                                                  \
  } while (0)

  // ---------------- prologue: stage Bs tile 0, load Wq tile 0 frags
  STAGE(0, 0, 0); STAGE(0, 0, 1); STAGE(0, 0, 2); STAGE(0, 0, 3);
  STAGE(0, 0, 4); STAGE(0, 0, 5); STAGE(0, 0, 6); STAGE(0, 0, 7);
  bf16x8 wqC0 = WQF(0, 0), wqC1 = WQF(0, 1);
  bf16x8 wqN0, wqN1;
  __syncthreads();   // drains stage loads (compiler emits vmcnt(0) before barrier)

  // ---------------- main loop: 64 K-tiles, unrolled by 2 for static buffers
  for (int u = 0; u < 32; u++) {
    TILE(0, 1, wqC0, wqC1, wqN0, wqN1, 2 * u);
    TILE(1, 0, wqN0, wqN1, wqC0, wqC1, 2 * u + 1);
  }

  // ---------------- epilogue: C/D layout col=lane&31, row=(reg&3)+8*(reg>>2)+4*l5
#pragma unroll
  for (int rg = 0; rg < 2; rg++) {
#pragma unroll
    for (int fn = 0; fn < 4; fn++) {
      const int colb = col0 + wn + fn * 32 + l31;
      const int rowb = row0 + wrow + rg * 32 + 4 * l5;
#pragma unroll
      for (int reg = 0; reg < 16; reg++) {
        int row = rowb + (reg & 3) + 8 * (reg >> 2);
        C[row * N_COLS + colb] = acc[rg][fn][reg];
      }
    }
  }
}

// ---------------------------------------------------------------- launch
extern "C" void kernel_launch(void* const* d_in, const int* in_sizes, int n_in,
                              void* d_out, int out_size, void* d_ws, size_t ws_size,
                              hipStream_t stream) {
  const float* x  = (const float*)d_in[0];   // 32*512*10
  const float* qp = (const float*)d_in[1];   // 10
  const float* W1 = (const float*)d_in[2];   // 4096*10
  const float* W2 = (const float*)d_in[3];   // 1024*4096
  float* out = (float*)d_out;                // 32*512*1024 fp32

  char* ws = (char*)d_ws;
  __hip_bfloat16* W2b = (__hip_bfloat16*)ws;                 // 8388608 B
  __hip_bfloat16* Wq  = (__hip_bfloat16*)(ws + 8388608);     // 131072 B (4096x16)
  __hip_bfloat16* Qb  = (__hip_bfloat16*)(ws + 8519680);     // 524288 B (16384x16)

  prep<<<4176, 256, 0, stream>>>(W1, W2, x, qp, W2b, Wq, Qb);
  gemm_fused<<<(M_ROWS / 128) * (N_COLS / 256), 256, 0, stream>>>(Qb, Wq, W2b, out);
}

// Round 11
// 208.602 us; speedup vs baseline: 1.1267x; 1.0259x over previous
//
#include <hip/hip_runtime.h>
#include <hip/hip_bf16.h>

typedef __bf16 bf16x8 __attribute__((ext_vector_type(8)));
typedef float f32x16 __attribute__((ext_vector_type(16)));

#define NQ     10
#define M_ROWS 16384
#define N_COLS 1024
#define K_DIM  4096

// ---------------------------------------------------------------- helpers
__device__ __forceinline__ void gload_lds16(const __hip_bfloat16* g, __hip_bfloat16* l) {
  __builtin_amdgcn_global_load_lds(
      (const __attribute__((address_space(1))) void*)g,
      (__attribute__((address_space(3))) void*)l,
      16, 0, 0);
}

// relu both + pack to 2xbf16 (lo=a, hi=b): 2x v_max_f32 + HW v_cvt_pk_bf16_f32.
// (R6 win, PROVEN.  R9's post-pack v_pk_max_i16 variant produced NaN on HW.)
__device__ __forceinline__ unsigned pkrelu(float a, float b) {
  float x = fmaxf(a, 0.f), y = fmaxf(b, 0.f);
  unsigned r;
  asm("v_cvt_pk_bf16_f32 %0, %1, %2" : "=v"(r) : "v"(x), "v"(y));
  return r;
}

__device__ __forceinline__ bf16x8 mkfrag(unsigned a, unsigned b, unsigned c, unsigned d) {
  union { unsigned u[4]; bf16x8 v; } f;
  f.u[0] = a; f.u[1] = b; f.u[2] = c; f.u[3] = d;
  return f.v;
}

// ---------------------------------------------------------------- prep (fused)
// blocks [0,4096): W2 fp32->bf16
// blocks [4096,4112): Wq slot s holds W1 row pi(s) (pi = in-32-block bit perm:
//   out[4]=s[3], out[3]=s[2], out[2]=s[4], out[1:0]=s[1:0]) so the mini-MFMA's
//   D-reg layout IS the main-MFMA A-frag layout (no permlane, no reorder).
// blocks [4112,4176): Qb[row][0..15] = bf16(q_j(row)) closed-form, 0 pad
__global__ void __launch_bounds__(256) prep(const float* __restrict__ W1,
                                            const float* __restrict__ W2,
                                            const float* __restrict__ x,
                                            const float* __restrict__ qp,
                                            __hip_bfloat16* __restrict__ W2b,
                                            __hip_bfloat16* __restrict__ Wq,
                                            __hip_bfloat16* __restrict__ Qb) {
  const int b = blockIdx.x;
  const int tid = threadIdx.x;
  if (b < 4096) {
    int i = (b * 256 + tid) * 4;
    float4 v = *(const float4*)(W2 + i);
    union { __hip_bfloat16 h[4]; uint2 u; } p;
    p.h[0] = __float2bfloat16(v.x);
    p.h[1] = __float2bfloat16(v.y);
    p.h[2] = __float2bfloat16(v.z);
    p.h[3] = __float2bfloat16(v.w);
    *(uint2*)(W2b + i) = p.u;
  } else if (b < 4112) {
    int slot = (b - 4096) * 256 + tid;
    int s5 = slot & 31;
    int src = (slot & ~31) | (((s5 >> 3) & 1) << 4) | (((s5 >> 2) & 1) << 3) |
              (((s5 >> 4) & 1) << 2) | (s5 & 3);
    union { __hip_bfloat16 h[16]; uint4 u[2]; } p;
#pragma unroll
    for (int j = 0; j < NQ; j++) p.h[j] = __float2bfloat16(W1[src * NQ + j]);
#pragma unroll
    for (int j = NQ; j < 16; j++) p.h[j] = __float2bfloat16(0.f);
    *(uint4*)(Wq + slot * 16) = p.u[0];
    *(uint4*)(Wq + slot * 16 + 8) = p.u[1];
  } else {
    int row = (b - 4112) * 256 + tid;
    float c[NQ];
#pragma unroll
    for (int j = 0; j < NQ; j++) c[j] = cosf(x[row * NQ + j] + qp[j]);
    float q[NQ];
    float prod19 = 1.f;
#pragma unroll
    for (int j = 1; j < NQ; j++) prod19 *= c[j];
    q[0] = prod19;
    float pref = c[0];
#pragma unroll
    for (int k = 1; k < NQ; k++) { pref *= c[k]; q[k] = pref; }
    union { __hip_bfloat16 h[16]; uint4 u[2]; } p;
#pragma unroll
    for (int j = 0; j < NQ; j++) p.h[j] = __float2bfloat16(q[j]);
#pragma unroll
    for (int j = NQ; j < 16; j++) p.h[j] = __float2bfloat16(0.f);
    *(uint4*)(Qb + row * 16) = p.u[0];
    *(uint4*)(Qb + row * 16 + 8) = p.u[1];
  }
}

// ---------------------------------------------------------------- fused gemm
// C = relu(Q @ W1^T) @ W2^T.  256x256 block tile, 512 threads / 8 waves
// arranged 4 (rows) x 2 (cols): wave tile 64x128, acc[2][4] f32x16.
// Grid 256 = 1 block/CU; each XCD owns one 256-col B panel (2 MB, L2-fit).
//
// R11: PARITY ANTI-PHASING.  R6/R10's wall = MFMA-pipe + LDS-pipe SUM (not
// max): in-order issue makes each wave alternate {ds_reads -> lgkm stall ->
// MFMAs}, and the 2 waves/SIMD run identical barrier-released code, so both
// hit the ds-phase together (matrix pipe idles) then the MFMA phase together
// (LDS pipe idles).  R8 proved 4 waves/SIMD breaks lockstep (pipe-sum 104)
// but costs 2x mini redundancy.  Here: the SIMD-partner waves (parity =
// (wave>>2)&1, partners are w and w+4 under the w%4 SIMD mapping) process
// the tile's two independent kki-halves in OPPOSITE order -- Wq slots
// loaded swapped, swizzle chunks rotated (ch2,ch3,ch0,ch1) -- so one wave's
// conv/mini phase overlaps its partner's ds/MFMA phase by construction.
// Zero extra work, ~zero extra registers; K-slice accumulation reorder is
// a bounded fp change.  A never touches LDS (R4); pi-permuted Wq (R5);
// HW cvt_pk relu/pack (R6); ONE __syncthreads per K-tile.
__global__ void __launch_bounds__(512, 2) gemm_fused(const __hip_bfloat16* __restrict__ Qb,
                                                     const __hip_bfloat16* __restrict__ Wq,
                                                     const __hip_bfloat16* __restrict__ B,
                                                     float* __restrict__ C) {
  __shared__ __align__(16) __hip_bfloat16 Bs[2][256 * 64];   // 2 x 32 KB

  const int tid  = threadIdx.x;
  const int wave = tid >> 6;           // 0..7
  const int lane = tid & 63;
  const int l31  = lane & 31;
  const int l5   = lane >> 5;
  const int l7   = l31 & 7;
  const int wrow = (wave >> 1) * 64;   // 4 row bands x 64
  const int wn   = (wave & 1) * 128;   // 2 col halves x 128

  // parity: SIMD partners (w, w+4) get opposite kki-half order
  const int par  = (wave >> 2) & 1;

  // XCD decode: 2 XCDs per 256-col B panel, 32+32 row tiles
  const int L    = blockIdx.x;          // 256 blocks
  const int xcd  = L & 7;
  const int idx  = L >> 3;              // 0..31
  const int col0 = (xcd >> 1) * 256;
  const int row0 = (((xcd & 1) << 5) | idx) * 256;   // 64 row tiles

  const int ldrow = lane >> 3;                       // staging row 0..7
  const int ldc   = (((lane & 7) ^ ldrow) << 3);     // XOR slot for Bs staging

  // kt element-offsets for this wave's slot order: slot0 = kt(par), slot1 = other
  const int kA = par * 32;          // slot-0 kt offset (elements of 32-row group)
  const int kB = 32 - kA;           // slot-1 kt offset

  // hoisted ds_read swizzle chunks in this wave's processing order:
  // chA/chB belong to slot-0's kki pair, chC/chD to slot-1's
  const int chA = (((4 * par + 0 + l5) ^ l7) << 3);
  const int chB = (((4 * par + 2 + l5) ^ l7) << 3);
  const int chC = (((4 - 4 * par + 0 + l5) ^ l7) << 3);
  const int chD = (((4 - 4 * par + 2 + l5) ^ l7) << 3);
  const int bsoff = (wn + l31) * 64;    // element offset of this lane's row

  // mini-GEMM B-operand frags (loop-invariant): this wave's 2 row-groups
  const bf16x8 qbr0 = *(const bf16x8*)(Qb + (row0 + wrow +  0 + l31) * 16 + l5 * 8);
  const bf16x8 qbr1 = *(const bf16x8*)(Qb + (row0 + wrow + 32 + l31) * 16 + l5 * 8);

  // persistent zero C-operand for minis (zeroed once, never overwritten)
  f32x16 kZero;
#pragma unroll
  for (int r = 0; r < 16; r++) kZero[r] = 0.f;

  f32x16 acc[2][4];
#pragma unroll
  for (int i = 0; i < 2; i++)
#pragma unroll
    for (int j = 0; j < 4; j++)
#pragma unroll
      for (int r = 0; r < 16; r++) acc[i][j][r] = 0.f;

  // A-fragments: rg x {even,odd} kki of the current slot (rebuilt twice/tile)
  bf16x8 frE0, frO0, frE1, frO1;

#define MFMA_BF16 __builtin_amdgcn_mfma_f32_32x32x16_bf16

  // kt passed as precomputed element offset (kA/kB) -- parity-swapped slots
#define WQF(t, ktoff) (*(const bf16x8*)(Wq + ((t) * 64 + (ktoff) + l31) * 16 + l5 * 8))

  // wave w, instr i stages Bs rows [w*32+i*8, +8) x 64 k (XOR-swizzled source)
#define STAGE(bw, ts, i)                                                              \
  gload_lds16(B + (col0 + wave * 32 + (i) * 8 + ldrow) * K_DIM + (ts) * 64 + ldc,     \
              &Bs[bw][(wave * 32 + (i) * 8) * 64])

  // mini h-MFMA for one row-group -> even/odd-kki A-frags (pi-permuted Wq
  // makes D-reg order == frag order; kZero avoids per-mini zero-init)
#define MINIFR(QB, WQ, FRE, FRO) do {                                                 \
    f32x16 d_ = MFMA_BF16(WQ, QB, kZero, 0, 0, 0);                                    \
    FRE = mkfrag(pkrelu(d_[0],  d_[1]),  pkrelu(d_[2],  d_[3]),                       \
                 pkrelu(d_[8],  d_[9]),  pkrelu(d_[10], d_[11]));                     \
    FRO = mkfrag(pkrelu(d_[4],  d_[5]),  pkrelu(d_[6],  d_[7]),                       \
                 pkrelu(d_[12], d_[13]), pkrelu(d_[14], d_[15]));                     \
  } while (0)

  // one K=16 step: 4 Bs reads + 8 MFMAs (FR0 = rg0 frag, FR1 = rg1 frag).
  // f*2048 elements = 4096B const offsets fold into ds_read offset: immediates.
#define MAINK(cur, CH, FR0, FR1) do {                                                 \
    const __hip_bfloat16* bp_ = &Bs[cur][bsoff + (CH)];                               \
    const bf16x8 bb0 = *(const bf16x8*)(bp_ +    0);                                  \
    const bf16x8 bb1 = *(const bf16x8*)(bp_ + 2048);                                  \
    const bf16x8 bb2 = *(const bf16x8*)(bp_ + 4096);                                  \
    const bf16x8 bb3 = *(const bf16x8*)(bp_ + 6144);                                  \
    acc[0][0] = MFMA_BF16(FR0, bb0, acc[0][0], 0, 0, 0);                              \
    acc[0][1] = MFMA_BF16(FR0, bb1, acc[0][1], 0, 0, 0);                              \
    acc[0][2] = MFMA_BF16(FR0, bb2, acc[0][2], 0, 0, 0);                              \
    acc[0][3] = MFMA_BF16(FR0, bb3, acc[0][3], 0, 0, 0);                              \
    acc[1][0] = MFMA_BF16(FR1, bb0, acc[1][0], 0, 0, 0);                              \
    acc[1][1] = MFMA_BF16(FR1, bb1, acc[1][1], 0, 0, 0);                              \
    acc[1][2] = MFMA_BF16(FR1, bb2, acc[1][2], 0, 0, 0);                              \
    acc[1][3] = MFMA_BF16(FR1, bb3, acc[1][3], 0, 0, 0);                              \
  } while (0)

  // one K-tile: stage Bs for t+1, prefetch Wq[t+1] (parity-ordered slots),
  // minis+mains for t in this wave's slot order.  Tail (t=63) reads spill
  // into adjacent workspace regions (reads only, unused) -- no fault.
#define TILE(cur, nxt, WQ0, WQ1, WQP0, WQP1, t) do {                                  \
    STAGE(nxt, (t) + 1, 0); STAGE(nxt, (t) + 1, 1);                                   \
    STAGE(nxt, (t) + 1, 2); STAGE(nxt, (t) + 1, 3);                                   \
    WQP0 = WQF((t) + 1, kA); WQP1 = WQF((t) + 1, kB);                                 \
    MINIFR(qbr0, WQ0, frE0, frO0);                                                    \
    MINIFR(qbr1, WQ0, frE1, frO1);                                                    \
    MAINK(cur, chA, frE0, frE1);                                                      \
    MAINK(cur, chB, frO0, frO1);                                                      \
    MINIFR(qbr0, WQ1, frE0, frO0);                                                    \
    MINIFR(qbr1, WQ1, frE1, frO1);                                                    \
    MAINK(cur, chC, frE0, frE1);                                                      \
    MAINK(cur, chD, frO0, frO1);                                                      \
    __syncthreads();                                                                  \
  } while (0)

  // ---------------- prologue: stage Bs tile 0, load Wq tile 0 frags
  STAGE(0, 0, 0); STAGE(0, 0, 1); STAGE(0, 0, 2); STAGE(0, 0, 3);
  bf16x8 wqC0 = WQF(0, kA), wqC1 = WQF(0, kB);
  bf16x8 wqN0, wqN1;
  __syncthreads();   // drains stage loads (compiler emits vmcnt(0) before barrier)

  // ---------------- main loop: 64 K-tiles, unrolled by 2 for static buffers
  for (int u = 0; u < 32; u++) {
    TILE(0, 1, wqC0, wqC1, wqN0, wqN1, 2 * u);
    TILE(1, 0, wqN0, wqN1, wqC0, wqC1, 2 * u + 1);
  }

  // ---------------- epilogue: C/D layout col=lane&31, row=(reg&3)+8*(reg>>2)+4*l5
#pragma unroll
  for (int rg = 0; rg < 2; rg++) {
#pragma unroll
    for (int fn = 0; fn < 4; fn++) {
      const int colb = col0 + wn + fn * 32 + l31;
      const int rowb = row0 + wrow + rg * 32 + 4 * l5;
#pragma unroll
      for (int reg = 0; reg < 16; reg++) {
        int row = rowb + (reg & 3) + 8 * (reg >> 2);
        C[row * N_COLS + colb] = acc[rg][fn][reg];
      }
    }
  }
}

// ---------------------------------------------------------------- launch
extern "C" void kernel_launch(void* const* d_in, const int* in_sizes, int n_in,
                              void* d_out, int out_size, void* d_ws, size_t ws_size,
                              hipStream_t stream) {
  const float* x  = (const float*)d_in[0];   // 32*512*10
  const float* qp = (const float*)d_in[1];   // 10
  const float* W1 = (const float*)d_in[2];   // 4096*10
  const float* W2 = (const float*)d_in[3];   // 1024*4096
  float* out = (float*)d_out;                // 32*512*1024 fp32

  char* ws = (char*)d_ws;
  __hip_bfloat16* W2b = (__hip_bfloat16*)ws;                 // 8388608 B
  __hip_bfloat16* Wq  = (__hip_bfloat16*)(ws + 8388608);     // 131072 B (4096x16)
  __hip_bfloat16* Qb  = (__hip_bfloat16*)(ws + 8519680);     // 524288 B (16384x16)

  prep<<<4176, 256, 0, stream>>>(W1, W2, x, qp, W2b, Wq, Qb);
  gemm_fused<<<256, 512, 0, stream>>>(Qb, Wq, W2b, out);
}